// Round 1
// baseline (358.736 us; speedup 1.0000x reference)
//
#include <hip/hip_runtime.h>

#define NB 8192
#define ND 128
#define MARGINF 0.3f

__global__ __launch_bounds__(256) void triplet_scan(const float* __restrict__ a,
                                                    const float* __restrict__ p,
                                                    const float* __restrict__ n,
                                                    float* __restrict__ row_loss) {
    __shared__ __align__(16) float a_s[4][ND];
    const int wave = threadIdx.x >> 6;
    const int lane = threadIdx.x & 63;
    const int row  = blockIdx.x * 4 + wave;

    // Load this wave's a-row (coalesced), stage to LDS for per-lane dots.
    float a0 = a[(size_t)row * ND + lane];
    float a1 = a[(size_t)row * ND + lane + 64];
    a_s[wave][lane]      = a0;
    a_s[wave][lane + 64] = a1;

    // dist_ap = dot(a_i, p_i) via wave shuffle reduce (all lanes get the sum).
    float part = a0 * p[(size_t)row * ND + lane] + a1 * p[(size_t)row * ND + lane + 64];
    #pragma unroll
    for (int off = 32; off; off >>= 1) part += __shfl_xor(part, off, 64);
    const float dist_ap = part;
    const float thresh  = dist_ap + MARGINF;

    __syncthreads();  // a_s visible (also covers cross-wave LDS ordering)

    const float4* as4 = (const float4*)a_s[wave];
    const float4* n4  = (const float4*)n;

    float dist_an = 0.f;
    float diag    = 0.f;
    bool  found   = false;
    const int diag_tile = row >> 6;
    const int diag_lane = row & 63;

    for (int t = 0; t < NB / 64; ++t) {
        const int col = (t << 6) + lane;
        const float4* np4 = n4 + (size_t)col * (ND / 4);
        float acc[4] = {0.f, 0.f, 0.f, 0.f};
        #pragma unroll
        for (int d = 0; d < ND / 4; d += 4) {
            #pragma unroll
            for (int k = 0; k < 4; ++k) {
                float4 av = as4[d + k];   // LDS broadcast (same addr all lanes)
                float4 nv = np4[d + k];   // per-lane column, L1/L2 cached
                acc[k] += av.x * nv.x + av.y * nv.y + av.z * nv.z + av.w * nv.w;
            }
        }
        const float val = (acc[0] + acc[1]) + (acc[2] + acc[3]);

        if (t == diag_tile) diag = __shfl(val, diag_lane, 64);  // an[i,i] for free

        const unsigned long long hit = __ballot(val < thresh);
        if (hit) {  // wave-uniform branch
            const int fl = __ffsll(hit) - 1;   // lowest lane = lowest column = first True
            dist_an = __shfl(val, fl, 64);
            found = true;
            break;
        }
    }
    if (!found) dist_an = diag;

    if (lane == 0) {
        const float l = dist_an - dist_ap + MARGINF;
        row_loss[row] = l > 0.f ? l : 0.f;
    }
}

__global__ __launch_bounds__(256) void reduce_loss(const float* __restrict__ row_loss,
                                                   float* __restrict__ out) {
    __shared__ float s[256];
    float sum = 0.f;
    // Fixed-order strided accumulation: deterministic across replays.
    for (int i = threadIdx.x; i < NB; i += 256) sum += row_loss[i];
    s[threadIdx.x] = sum;
    __syncthreads();
    #pragma unroll
    for (int off = 128; off; off >>= 1) {
        if ((int)threadIdx.x < off) s[threadIdx.x] += s[threadIdx.x + off];
        __syncthreads();
    }
    if (threadIdx.x == 0) out[0] = s[0] / (float)NB;
}

extern "C" void kernel_launch(void* const* d_in, const int* in_sizes, int n_in,
                              void* d_out, int out_size, void* d_ws, size_t ws_size,
                              hipStream_t stream) {
    const float* a = (const float*)d_in[0];
    const float* p = (const float*)d_in[1];
    const float* n = (const float*)d_in[2];
    float* row_loss = (float*)d_ws;   // 8192 floats = 32 KB scratch
    float* out = (float*)d_out;

    triplet_scan<<<NB / 4, 256, 0, stream>>>(a, p, n, row_loss);
    reduce_loss<<<1, 256, 0, stream>>>(row_loss, out);
}

// Round 2
// 179.022 us; speedup vs baseline: 2.0039x; 2.0039x over previous
//
#include <hip/hip_runtime.h>

#define NB 8192
#define ND 128
#define MARGINF 0.3f
#define CAP_TILES 4        // phase-1 scans 4*64 = 256 columns
#define P2_BLOCKS 128

// d_ws layout:
//   [0]                 int   count        (worklist size)
//   [256 B]             int   list[8192]   (unresolved rows)
//   [40960 B]           float row_loss[8192]
// total 72 KB

__global__ __launch_bounds__(256) void triplet_scan(const float* __restrict__ a,
                                                    const float* __restrict__ p,
                                                    const float* __restrict__ n,
                                                    int* __restrict__ count,
                                                    int* __restrict__ list,
                                                    float* __restrict__ row_loss) {
    __shared__ __align__(16) float a_s[4][ND];
    const int wave = threadIdx.x >> 6;
    const int lane = threadIdx.x & 63;
    const int row  = blockIdx.x * 4 + wave;

    float a0 = a[(size_t)row * ND + lane];
    float a1 = a[(size_t)row * ND + lane + 64];
    a_s[wave][lane]      = a0;
    a_s[wave][lane + 64] = a1;

    // dist_ap = dot(a_i, p_i), all lanes get the sum
    float part = a0 * p[(size_t)row * ND + lane] + a1 * p[(size_t)row * ND + lane + 64];
    #pragma unroll
    for (int off = 32; off; off >>= 1) part += __shfl_xor(part, off, 64);
    const float dist_ap = part;
    const float thresh  = dist_ap + MARGINF;

    __syncthreads();

    const float4* as4 = (const float4*)a_s[wave];
    const float4* n4  = (const float4*)n;

    for (int t = 0; t < CAP_TILES; ++t) {
        const int col = (t << 6) + lane;
        const float4* np4 = n4 + (size_t)col * (ND / 4);
        float acc[4] = {0.f, 0.f, 0.f, 0.f};
        #pragma unroll
        for (int d = 0; d < ND / 4; d += 4) {
            #pragma unroll
            for (int k = 0; k < 4; ++k) {
                float4 av = as4[d + k];
                float4 nv = np4[d + k];
                acc[k] += av.x * nv.x + av.y * nv.y + av.z * nv.z + av.w * nv.w;
            }
        }
        const float val = (acc[0] + acc[1]) + (acc[2] + acc[3]);

        const unsigned long long hit = __ballot(val < thresh);
        if (hit) {  // wave-uniform
            const int fl = __ffsll(hit) - 1;           // lowest lane = first column
            const float dist_an = __shfl(val, fl, 64);
            if (lane == 0) {
                const float l = dist_an - dist_ap + MARGINF;
                row_loss[row] = l > 0.f ? l : 0.f;
            }
            return;
        }
    }
    // unresolved within cap -> phase 2
    if (lane == 0) list[atomicAdd(count, 1)] = row;
}

// One block per unresolved row: parallel scan of all 8192 columns,
// first hit via min-index block reduction; diagonal captured in-sweep.
__global__ __launch_bounds__(256) void triplet_deep(const float* __restrict__ a,
                                                    const float* __restrict__ p,
                                                    const float* __restrict__ n,
                                                    const int* __restrict__ count,
                                                    const int* __restrict__ list,
                                                    float* __restrict__ row_loss) {
    __shared__ __align__(16) float a_s[ND];
    __shared__ float s_val[256];
    __shared__ int   s_idx[256];
    __shared__ float s_diag;
    const int tid = threadIdx.x;
    const int cnt = *count;                       // uniform across block

    for (int w = blockIdx.x; w < cnt; w += gridDim.x) {
        __syncthreads();                          // guard LDS reuse across iterations
        const int row = list[w];
        if (tid < ND) a_s[tid] = a[(size_t)row * ND + tid];
        float pp = 0.f;
        if (tid < ND) pp = a[(size_t)row * ND + tid] * p[(size_t)row * ND + tid];
        s_val[tid] = pp;
        __syncthreads();
        #pragma unroll
        for (int off = 128; off; off >>= 1) {
            if (tid < off) s_val[tid] += s_val[tid + off];
            __syncthreads();
        }
        const float dist_ap = s_val[0];           // valid: after final sync
        const float thresh  = dist_ap + MARGINF;
        __syncthreads();                          // before s_val reuse below

        const float4* as4 = (const float4*)a_s;
        int   best_i = 0x7fffffff;
        float best_v = 0.f;
        for (int r = 0; r < NB / 256; ++r) {
            const int j = r * 256 + tid;
            const float4* np4 = (const float4*)(n + (size_t)j * ND);
            float acc[4] = {0.f, 0.f, 0.f, 0.f};
            #pragma unroll
            for (int d = 0; d < ND / 4; d += 4) {
                #pragma unroll
                for (int k = 0; k < 4; ++k) {
                    float4 av = as4[d + k];
                    float4 nv = np4[d + k];
                    acc[k] += av.x * nv.x + av.y * nv.y + av.z * nv.z + av.w * nv.w;
                }
            }
            const float val = (acc[0] + acc[1]) + (acc[2] + acc[3]);
            if (j == row) s_diag = val;           // exactly one writer
            if (val < thresh && best_i == 0x7fffffff) { best_i = j; best_v = val; }
        }
        __syncthreads();                          // s_diag visible; s_val free
        s_val[tid] = best_v;
        s_idx[tid] = best_i;
        __syncthreads();
        #pragma unroll
        for (int off = 128; off; off >>= 1) {
            if (tid < off && s_idx[tid + off] < s_idx[tid]) {
                s_idx[tid] = s_idx[tid + off];
                s_val[tid] = s_val[tid + off];
            }
            __syncthreads();
        }
        if (tid == 0) {
            const float dist_an = (s_idx[0] != 0x7fffffff) ? s_val[0] : s_diag;
            const float l = dist_an - dist_ap + MARGINF;
            row_loss[row] = l > 0.f ? l : 0.f;
        }
    }
}

__global__ __launch_bounds__(256) void reduce_loss(const float* __restrict__ row_loss,
                                                   float* __restrict__ out) {
    __shared__ float s[256];
    float sum = 0.f;
    for (int i = threadIdx.x; i < NB; i += 256) sum += row_loss[i];  // fixed order
    s[threadIdx.x] = sum;
    __syncthreads();
    #pragma unroll
    for (int off = 128; off; off >>= 1) {
        if ((int)threadIdx.x < off) s[threadIdx.x] += s[threadIdx.x + off];
        __syncthreads();
    }
    if (threadIdx.x == 0) out[0] = s[0] / (float)NB;
}

extern "C" void kernel_launch(void* const* d_in, const int* in_sizes, int n_in,
                              void* d_out, int out_size, void* d_ws, size_t ws_size,
                              hipStream_t stream) {
    const float* a = (const float*)d_in[0];
    const float* p = (const float*)d_in[1];
    const float* n = (const float*)d_in[2];
    char* ws = (char*)d_ws;
    int*   count    = (int*)ws;
    int*   list     = (int*)(ws + 256);
    float* row_loss = (float*)(ws + 40960);
    float* out = (float*)d_out;

    hipMemsetAsync(count, 0, sizeof(int), stream);
    triplet_scan<<<NB / 4, 256, 0, stream>>>(a, p, n, count, list, row_loss);
    triplet_deep<<<P2_BLOCKS, 256, 0, stream>>>(a, p, n, count, list, row_loss);
    reduce_loss<<<1, 256, 0, stream>>>(row_loss, out);
}

// Round 3
// 105.249 us; speedup vs baseline: 3.4084x; 1.7009x over previous
//
#include <hip/hip_runtime.h>

#define NB 8192
#define ND 128
#define MARGINF 0.3f
#define CAP_TILES 2        // phase-1 scans 2*64 = 128 columns
#define NCHUNK 32          // phase-2: 32 chunks x 256 columns
#define P2_GRID 2048

// d_ws layout (bytes):
//   [0]      int   count
//   [1024]   int   list[8192]       unresolved rows
//   [33792]  float dap[8192]        dist_ap for unresolved rows (by list idx)
//   [66560]  uint  idxmin[8192]     first-hit column (by list idx), 0xFFFFFFFF = none
//   [99328]  float row_loss[8192]
// total ~129 KB

__global__ __launch_bounds__(256) void triplet_scan(const float* __restrict__ a,
                                                    const float* __restrict__ p,
                                                    const float* __restrict__ n,
                                                    int* __restrict__ count,
                                                    int* __restrict__ list,
                                                    float* __restrict__ dap,
                                                    float* __restrict__ row_loss) {
    __shared__ __align__(16) float a_s[4][ND];
    const int wave = threadIdx.x >> 6;
    const int lane = threadIdx.x & 63;
    const int row  = blockIdx.x * 4 + wave;

    float a0 = a[(size_t)row * ND + lane];
    float a1 = a[(size_t)row * ND + lane + 64];
    a_s[wave][lane]      = a0;
    a_s[wave][lane + 64] = a1;

    float part = a0 * p[(size_t)row * ND + lane] + a1 * p[(size_t)row * ND + lane + 64];
    #pragma unroll
    for (int off = 32; off; off >>= 1) part += __shfl_xor(part, off, 64);
    const float dist_ap = part;
    const float thresh  = dist_ap + MARGINF;

    __syncthreads();

    const float4* as4 = (const float4*)a_s[wave];
    const float4* n4  = (const float4*)n;

    for (int t = 0; t < CAP_TILES; ++t) {
        const int col = (t << 6) + lane;
        const float4* np4 = n4 + (size_t)col * (ND / 4);
        float acc[4] = {0.f, 0.f, 0.f, 0.f};
        #pragma unroll
        for (int d = 0; d < ND / 4; d += 4) {
            #pragma unroll
            for (int k = 0; k < 4; ++k) {
                float4 av = as4[d + k];
                float4 nv = np4[d + k];
                acc[k] += av.x * nv.x + av.y * nv.y + av.z * nv.z + av.w * nv.w;
            }
        }
        const float val = (acc[0] + acc[1]) + (acc[2] + acc[3]);

        const unsigned long long hit = __ballot(val < thresh);
        if (hit) {  // wave-uniform
            const int fl = __ffsll(hit) - 1;
            const float dist_an = __shfl(val, fl, 64);
            if (lane == 0) {
                const float l = dist_an - dist_ap + MARGINF;
                row_loss[row] = l > 0.f ? l : 0.f;
            }
            return;
        }
    }
    if (lane == 0) {
        const int k = atomicAdd(count, 1);
        list[k] = row;
        dap[k]  = dist_ap;
    }
}

// Phase 2: pairs (w, chunk); one column per thread; first-hit via unsigned atomicMin.
__global__ __launch_bounds__(256) void triplet_cols(const float* __restrict__ a,
                                                    const float* __restrict__ n,
                                                    const int* __restrict__ count,
                                                    const int* __restrict__ list,
                                                    const float* __restrict__ dap,
                                                    unsigned int* __restrict__ idxmin) {
    __shared__ __align__(16) float a_s[ND];
    __shared__ float s_thresh;
    const int tid = threadIdx.x;
    const int cnt = *count;
    const int npairs = cnt * NCHUNK;

    for (int pair = blockIdx.x; pair < npairs; pair += gridDim.x) {
        const int w     = pair >> 5;          // / NCHUNK
        const int chunk = pair & (NCHUNK - 1);
        const int row   = list[w];
        __syncthreads();                      // protect a_s/s_thresh reuse
        if (tid < ND) a_s[tid] = a[(size_t)row * ND + tid];
        if (tid == 0) s_thresh = dap[w] + MARGINF;
        __syncthreads();

        const int j = chunk * 256 + tid;
        const float4* as4 = (const float4*)a_s;
        const float4* np4 = (const float4*)(n + (size_t)j * ND);
        float acc[4] = {0.f, 0.f, 0.f, 0.f};
        #pragma unroll
        for (int d = 0; d < ND / 4; d += 4) {
            #pragma unroll
            for (int k = 0; k < 4; ++k) {
                float4 av = as4[d + k];
                float4 nv = np4[d + k];
                acc[k] += av.x * nv.x + av.y * nv.y + av.z * nv.z + av.w * nv.w;
            }
        }
        const float val = (acc[0] + acc[1]) + (acc[2] + acc[3]);
        if (val < s_thresh) atomicMin(&idxmin[w], (unsigned int)j);
    }
}

// Fixup: one wave per unresolved row; recompute an[row, j] (j = first hit or diag).
__global__ __launch_bounds__(256) void triplet_fixup(const float* __restrict__ a,
                                                     const float* __restrict__ n,
                                                     const int* __restrict__ count,
                                                     const int* __restrict__ list,
                                                     const float* __restrict__ dap,
                                                     const unsigned int* __restrict__ idxmin,
                                                     float* __restrict__ row_loss) {
    const int lane  = threadIdx.x & 63;
    const int wg    = (blockIdx.x * 256 + threadIdx.x) >> 6;   // global wave id
    const int nwave = (gridDim.x * 256) >> 6;
    const int cnt   = *count;

    for (int w = wg; w < cnt; w += nwave) {
        const int row = list[w];
        const unsigned int u = idxmin[w];
        const int j = (u == 0xFFFFFFFFu) ? row : (int)u;
        const float a0 = a[(size_t)row * ND + lane];
        const float a1 = a[(size_t)row * ND + lane + 64];
        float part = a0 * n[(size_t)j * ND + lane] + a1 * n[(size_t)j * ND + lane + 64];
        #pragma unroll
        for (int off = 32; off; off >>= 1) part += __shfl_xor(part, off, 64);
        if (lane == 0) {
            const float l = part - dap[w] + MARGINF;
            row_loss[row] = l > 0.f ? l : 0.f;
        }
    }
}

__global__ __launch_bounds__(256) void reduce_loss(const float* __restrict__ row_loss,
                                                   float* __restrict__ out) {
    __shared__ float s[256];
    float sum = 0.f;
    for (int i = threadIdx.x; i < NB; i += 256) sum += row_loss[i];  // fixed order
    s[threadIdx.x] = sum;
    __syncthreads();
    #pragma unroll
    for (int off = 128; off; off >>= 1) {
        if ((int)threadIdx.x < off) s[threadIdx.x] += s[threadIdx.x + off];
        __syncthreads();
    }
    if (threadIdx.x == 0) out[0] = s[0] / (float)NB;
}

extern "C" void kernel_launch(void* const* d_in, const int* in_sizes, int n_in,
                              void* d_out, int out_size, void* d_ws, size_t ws_size,
                              hipStream_t stream) {
    const float* a = (const float*)d_in[0];
    const float* p = (const float*)d_in[1];
    const float* n = (const float*)d_in[2];
    char* ws = (char*)d_ws;
    int*          count    = (int*)ws;
    int*          list     = (int*)(ws + 1024);
    float*        dap      = (float*)(ws + 33792);
    unsigned int* idxmin   = (unsigned int*)(ws + 66560);
    float*        row_loss = (float*)(ws + 99328);
    float* out = (float*)d_out;

    hipMemsetAsync(count, 0, sizeof(int), stream);
    hipMemsetAsync(idxmin, 0xFF, NB * sizeof(unsigned int), stream);
    triplet_scan <<<NB / 4, 256, 0, stream>>>(a, p, n, count, list, dap, row_loss);
    triplet_cols <<<P2_GRID, 256, 0, stream>>>(a, n, count, list, dap, idxmin);
    triplet_fixup<<<32, 256, 0, stream>>>(a, n, count, list, dap, idxmin, row_loss);
    reduce_loss  <<<1, 256, 0, stream>>>(row_loss, out);
}

// Round 4
// 53.930 us; speedup vs baseline: 6.6519x; 1.9516x over previous
//
#include <hip/hip_runtime.h>

#define NB 8192
#define ND 128
#define MARGINF 0.3f
#define CAP_TILES 4        // phase-1 scans 4*64 = 256 columns
#define NCHUNK 32          // phase-2: 32 chunks x 256 columns
#define P2_GRID 2048

// d_ws layout (bytes):
//   [0]      int   count
//   [1024]   int   list[8192]
//   [33792]  float dap[8192]
//   [66560]  uint  idxmin[8192]   (init'd by scan for k < count)
//   [99328]  float row_loss[8192]

__device__ __forceinline__ float dot4(float4 x, float4 y) {
    return x.x * y.x + x.y * y.y + x.z * y.z + x.w * y.w;
}

// Butterfly sum within each 32-lane half (offsets 1..16 keep bit5 fixed).
__device__ __forceinline__ float half_reduce(float v) {
    v += __shfl_xor(v, 1, 64);
    v += __shfl_xor(v, 2, 64);
    v += __shfl_xor(v, 4, 64);
    v += __shfl_xor(v, 8, 64);
    v += __shfl_xor(v, 16, 64);
    return v;
}

// Returns first (lowest) column in [0,64) given lane ownership col(L)=2*(L&31)+(L>>5).
__device__ __forceinline__ int first_col_from_mask(unsigned long long mask) {
    const unsigned int lo = (unsigned int)mask;          // even local cols 2*L
    const unsigned int hi = (unsigned int)(mask >> 32);  // odd local cols 2*(L-32)+1
    const int ce = lo ? 2 * (__ffs(lo) - 1)     : 0x7fffffff;
    const int co = hi ? 2 * (__ffs(hi) - 1) + 1 : 0x7fffffff;
    return ce < co ? ce : co;
}

__global__ __launch_bounds__(256) void triplet_scan(const float* __restrict__ a,
                                                    const float* __restrict__ p,
                                                    const float* __restrict__ n,
                                                    int* __restrict__ count,
                                                    int* __restrict__ list,
                                                    float* __restrict__ dap,
                                                    unsigned int* __restrict__ idxmin,
                                                    float* __restrict__ row_loss) {
    const int wave = threadIdx.x >> 6;
    const int lane = threadIdx.x & 63;
    const int row  = blockIdx.x * 4 + wave;
    const int q    = lane & 31;   // quarter-row position (float4 index)
    const int h    = lane >> 5;   // half: 0 -> even column, 1 -> odd column

    const float4 a4 = *(const float4*)(a + (size_t)row * ND + q * 4);
    const float4 p4 = *(const float4*)(p + (size_t)row * ND + q * 4);
    const float dist_ap = half_reduce(dot4(a4, p4));
    const float thresh  = dist_ap + MARGINF;

    for (int t = 0; t < CAP_TILES; ++t) {
        float myval = 0.f;
        #pragma unroll
        for (int k = 0; k < 32; ++k) {
            const int col = t * 64 + 2 * k + h;
            // Coalesced: wave covers 1024 contiguous bytes (2 rows of n).
            const float4 nv = *(const float4*)(n + (size_t)col * ND + q * 4);
            const float v = half_reduce(dot4(a4, nv));
            if (q == k) myval = v;   // lane L retains col 2*(L&31)+(L>>5)
        }
        const unsigned long long mask = __ballot(myval < thresh);
        if (mask) {  // wave-uniform
            const int c   = first_col_from_mask(mask);
            const int src = (c & 1) ? 32 + (c >> 1) : (c >> 1);
            const float dist_an = __shfl(myval, src, 64);
            if (lane == 0) {
                const float l = dist_an - dist_ap + MARGINF;
                row_loss[row] = l > 0.f ? l : 0.f;
            }
            return;
        }
    }
    if (lane == 0) {
        const int k = atomicAdd(count, 1);
        list[k]   = row;
        dap[k]    = dist_ap;
        idxmin[k] = 0xFFFFFFFFu;
    }
}

// Phase 2: pair = (unresolved row w, 256-col chunk); wave handles 64 cols.
__global__ __launch_bounds__(256) void triplet_cols(const float* __restrict__ a,
                                                    const float* __restrict__ n,
                                                    const int* __restrict__ count,
                                                    const int* __restrict__ list,
                                                    const float* __restrict__ dap,
                                                    unsigned int* __restrict__ idxmin) {
    const int wave = threadIdx.x >> 6;
    const int lane = threadIdx.x & 63;
    const int q    = lane & 31;
    const int h    = lane >> 5;
    const int cnt  = *count;
    const int npairs = cnt * NCHUNK;

    for (int pair = blockIdx.x; pair < npairs; pair += gridDim.x) {
        const int w     = pair >> 5;          // / NCHUNK
        const int chunk = pair & (NCHUNK - 1);
        const int row   = list[w];
        const float4 a4 = *(const float4*)(a + (size_t)row * ND + q * 4);
        const float thresh = dap[w] + MARGINF;
        const int base = chunk * 256 + wave * 64;

        float myval = 0.f;
        #pragma unroll
        for (int k = 0; k < 32; ++k) {
            const int col = base + 2 * k + h;
            const float4 nv = *(const float4*)(n + (size_t)col * ND + q * 4);
            const float v = half_reduce(dot4(a4, nv));  // same order as scan
            if (q == k) myval = v;
        }
        const unsigned long long mask = __ballot(myval < thresh);
        if (mask) {
            const int c = first_col_from_mask(mask);
            if (lane == 0) atomicMin(&idxmin[w], (unsigned int)(base + c));
        }
    }
}

// Fixup: one wave per unresolved row; recompute an[row, j] (j = first hit or diag).
__global__ __launch_bounds__(256) void triplet_fixup(const float* __restrict__ a,
                                                     const float* __restrict__ n,
                                                     const int* __restrict__ count,
                                                     const int* __restrict__ list,
                                                     const float* __restrict__ dap,
                                                     const unsigned int* __restrict__ idxmin,
                                                     float* __restrict__ row_loss) {
    const int lane  = threadIdx.x & 63;
    const int wg    = (blockIdx.x * 256 + threadIdx.x) >> 6;
    const int nwave = (gridDim.x * 256) >> 6;
    const int cnt   = *count;

    for (int w = wg; w < cnt; w += nwave) {
        const int row = list[w];
        const unsigned int u = idxmin[w];
        const int j = (u == 0xFFFFFFFFu) ? row : (int)u;
        const float a0 = a[(size_t)row * ND + lane];
        const float a1 = a[(size_t)row * ND + lane + 64];
        float part = a0 * n[(size_t)j * ND + lane] + a1 * n[(size_t)j * ND + lane + 64];
        #pragma unroll
        for (int off = 32; off; off >>= 1) part += __shfl_xor(part, off, 64);
        if (lane == 0) {
            const float l = part - dap[w] + MARGINF;
            row_loss[row] = l > 0.f ? l : 0.f;
        }
    }
}

__global__ __launch_bounds__(256) void reduce_loss(const float* __restrict__ row_loss,
                                                   float* __restrict__ out) {
    __shared__ float s[256];
    const float4* rl4 = (const float4*)row_loss;
    float sum = 0.f;
    #pragma unroll
    for (int i = 0; i < NB / 4 / 256; ++i) {   // 8 iterations, fixed order
        const float4 v = rl4[i * 256 + threadIdx.x];
        sum += (v.x + v.y) + (v.z + v.w);
    }
    s[threadIdx.x] = sum;
    __syncthreads();
    #pragma unroll
    for (int off = 128; off; off >>= 1) {
        if ((int)threadIdx.x < off) s[threadIdx.x] += s[threadIdx.x + off];
        __syncthreads();
    }
    if (threadIdx.x == 0) out[0] = s[0] / (float)NB;
}

extern "C" void kernel_launch(void* const* d_in, const int* in_sizes, int n_in,
                              void* d_out, int out_size, void* d_ws, size_t ws_size,
                              hipStream_t stream) {
    const float* a = (const float*)d_in[0];
    const float* p = (const float*)d_in[1];
    const float* n = (const float*)d_in[2];
    char* ws = (char*)d_ws;
    int*          count    = (int*)ws;
    int*          list     = (int*)(ws + 1024);
    float*        dap      = (float*)(ws + 33792);
    unsigned int* idxmin   = (unsigned int*)(ws + 66560);
    float*        row_loss = (float*)(ws + 99328);
    float* out = (float*)d_out;

    hipMemsetAsync(count, 0, sizeof(int), stream);
    triplet_scan <<<NB / 4, 256, 0, stream>>>(a, p, n, count, list, dap, idxmin, row_loss);
    triplet_cols <<<P2_GRID, 256, 0, stream>>>(a, n, count, list, dap, idxmin);
    triplet_fixup<<<32, 256, 0, stream>>>(a, n, count, list, dap, idxmin, row_loss);
    reduce_loss  <<<1, 256, 0, stream>>>(row_loss, out);
}